// Round 2
// baseline (1019.476 us; speedup 1.0000x reference)
//
#include <hip/hip_runtime.h>
#include <stdint.h>

#define M_DIM 2048
#define K_DIM 8192
#define N_Q   8192
#define N_KV  1024
#define BM    128
#define BN    128
#define BK    32
#define NIT   (K_DIM / BK)   // 256 K-iterations

typedef __bf16 bf16x8 __attribute__((ext_vector_type(8)));
typedef __bf16 bf16x2 __attribute__((ext_vector_type(2)));
typedef float  f32x4  __attribute__((ext_vector_type(4)));

// XOR swizzle of the 16B k-chunk index by row: frag ds_read_b128 stay ~2-way (free per m136)
__device__ __forceinline__ uint32_t swz(uint32_t r) { return ((r >> 1) ^ (r >> 3)) & 3u; }

// f32 pair -> packed bf16x2 (RNE); pattern-matches v_cvt_pk_bf16_f32 on gfx950
__device__ __forceinline__ uint32_t pack_bf16(float lo, float hi) {
    bf16x2 v = { (__bf16)lo, (__bf16)hi };
    return __builtin_bit_cast(uint32_t, v);
}

__global__ __launch_bounds__(256) void qkv_gemm(
    const float* __restrict__ x,
    const float* __restrict__ wq,
    const float* __restrict__ wk,
    const float* __restrict__ wv,
    float* __restrict__ out)
{
    // bf16 LDS tiles: rows of 32 bf16 (64B = 4 x 16B chunks), chunk index XOR-swizzled by row
    __shared__ __align__(16) uint16_t sA[BM * BK];   // [m][k]
    __shared__ __align__(16) uint16_t sB[BN * BK];   // [n][k] (transposed W tile)
    uint32_t* sAu = (uint32_t*)sA;
    uint32_t* sBu = (uint32_t*)sB;

    const uint32_t tid    = threadIdx.x;
    const uint32_t bid    = blockIdx.x;
    const uint32_t mt_blk = bid & 15;     // 16 consecutive blocks share one W column slab (L2 reuse)
    const uint32_t nt_blk = bid >> 4;     // 80 n-tiles
    const uint32_t m0     = mt_blk * BM;

    // ---- select weight matrix + output base (BN == HEAD_DIM == 128; boundaries divide) ----
    const size_t QSZ = (size_t)64 * M_DIM * 128;
    const size_t KSZ = (size_t)8  * M_DIM * 128;
    const float* Wsel;
    uint32_t ldW, col0;
    size_t obase;
    if (nt_blk < 64)      { Wsel = wq; ldW = N_Q;  col0 = nt_blk * 128;
                            obase = (size_t)nt_blk * M_DIM * 128; }
    else if (nt_blk < 72) { Wsel = wk; ldW = N_KV; col0 = (nt_blk - 64) * 128;
                            obase = QSZ + (size_t)(nt_blk - 64) * M_DIM * 128; }
    else                  { Wsel = wv; ldW = N_KV; col0 = (nt_blk - 72) * 128;
                            obase = QSZ + KSZ + (size_t)(nt_blk - 72) * M_DIM * 128; }

    // ---- A staging map: load i=0..3: row = i*32 + (tid>>3), k = (tid&7)*4 .. +3 (float4) ----
    const float* agp = x + (size_t)(m0 + (tid >> 3)) * K_DIM + (tid & 7) * 4;
    // LDS write (dword index): r*16 + ((kc ^ swz(r))*4) + (tid&1)*2, kc = (tid&7)>>1
    uint32_t a_wr[4];
    #pragma unroll
    for (int i = 0; i < 4; ++i) {
        uint32_t r = i * 32 + (tid >> 3);
        a_wr[i] = r * 16 + ((((tid >> 1) & 3) ^ swz(r)) * 4) + (tid & 1) * 2;
    }

    // ---- B staging map: rows bk,bk+1 = (tid>>4)*2, cols bn0..bn0+7 = (tid&15)*8 ----
    const uint32_t bk  = (tid >> 4) * 2;
    const uint32_t bn0 = (tid & 15) * 8;
    const float* bgp = Wsel + (size_t)bk * ldW + col0 + bn0;
    const uint32_t bkc = bk >> 3;           // logical k-chunk of this thread's row pair
    const uint32_t bkd = (bk & 7) >> 1;     // dword within chunk

    // ---- prefetch tile 0 into registers ----
    f32x4 apre[4], bpre[4];
    #pragma unroll
    for (int i = 0; i < 4; ++i) apre[i] = *(const f32x4*)(agp + (size_t)i * 32 * K_DIM);
    bpre[0] = *(const f32x4*)(bgp);
    bpre[1] = *(const f32x4*)(bgp + 4);
    bpre[2] = *(const f32x4*)(bgp + ldW);
    bpre[3] = *(const f32x4*)(bgp + ldW + 4);

    // ---- wave / lane decomposition (2x2 waves, each 64x64) ----
    const uint32_t lane = tid & 63;
    const uint32_t wid  = tid >> 6;
    const uint32_t wm   = (wid >> 1) * 64;
    const uint32_t wn   = (wid & 1) * 64;
    const uint32_t l15  = lane & 15;
    const uint32_t quad = lane >> 4;

    f32x4 acc[4][4] = {};

    // fragment read offsets (ushort units): row*32 + (chunk^swz(row))*8
    uint32_t a_off[4], b_off[4];
    #pragma unroll
    for (int t = 0; t < 4; ++t) {
        uint32_t ar = wm + t * 16 + l15;
        a_off[t] = ar * BK + ((quad ^ swz(ar)) * 8);
        uint32_t br = wn + t * 16 + l15;
        b_off[t] = br * BK + ((quad ^ swz(br)) * 8);
    }

    const float* agp_n = agp + BK;                   // next iter pointers
    const float* bgp_n = bgp + (size_t)BK * ldW;

    for (uint32_t kt = 0; kt < NIT; ++kt) {
        __syncthreads();   // prior iter's frag reads done -> LDS reusable

        // A tile: convert + write (2 dwords = 4 bf16 per load, 8-B aligned)
        #pragma unroll
        for (int i = 0; i < 4; ++i) {
            uint2 w;
            w.x = pack_bf16(apre[i].x, apre[i].y);
            w.y = pack_bf16(apre[i].z, apre[i].w);
            *(uint2*)&sAu[a_wr[i]] = w;
        }
        // B tile: transpose-repack; dword j holds W[bk][n], W[bk+1][n] for n = bn0+j
        {
            const float* pk0 = (const float*)&bpre[0];   // row bk  cols 0..7
            const float* pk1 = (const float*)&bpre[2];   // row bk+1 cols 0..7
            #pragma unroll
            for (int j = 0; j < 8; ++j) {
                uint32_t n = bn0 + j;
                sBu[n * 16 + ((bkc ^ swz(n)) * 4) + bkd] = pack_bf16(pk0[j], pk1[j]);
            }
        }

        // prefetch next tile (latency hidden under this iter's MFMAs)
        if (kt + 1 < NIT) {
            #pragma unroll
            for (int i = 0; i < 4; ++i) apre[i] = *(const f32x4*)(agp_n + (size_t)i * 32 * K_DIM);
            bpre[0] = *(const f32x4*)(bgp_n);
            bpre[1] = *(const f32x4*)(bgp_n + 4);
            bpre[2] = *(const f32x4*)(bgp_n + ldW);
            bpre[3] = *(const f32x4*)(bgp_n + ldW + 4);
            agp_n += BK;
            bgp_n += (size_t)BK * ldW;
        }

        __syncthreads();   // staging writes visible

        bf16x8 af[4], bf[4];
        #pragma unroll
        for (int t = 0; t < 4; ++t) {
            af[t] = *(const bf16x8*)(sA + a_off[t]);
            bf[t] = *(const bf16x8*)(sB + b_off[t]);
        }
        #pragma unroll
        for (int mt = 0; mt < 4; ++mt)
            #pragma unroll
            for (int nt = 0; nt < 4; ++nt)
                acc[mt][nt] = __builtin_amdgcn_mfma_f32_16x16x32_bf16(
                    af[mt], bf[nt], acc[mt][nt], 0, 0, 0);
    }

    // ---- epilogue: block covers one head's [m0:m0+128, 0:128) slab (contiguous, f32) ----
    // C/D layout: col = lane&15, row = quad*4 + reg (m89/m91 verified)
    float* op = out + obase + (size_t)m0 * 128;
    #pragma unroll
    for (int mt = 0; mt < 4; ++mt) {
        #pragma unroll
        for (int r = 0; r < 4; ++r) {
            uint32_t row = wm + mt * 16 + quad * 4 + r;
            #pragma unroll
            for (int nt = 0; nt < 4; ++nt) {
                uint32_t col = wn + nt * 16 + l15;
                op[(size_t)row * 128 + col] = acc[mt][nt][r];
            }
        }
    }
}

extern "C" void kernel_launch(void* const* d_in, const int* in_sizes, int n_in,
                              void* d_out, int out_size, void* d_ws, size_t ws_size,
                              hipStream_t stream) {
    const float* x  = (const float*)d_in[0];
    const float* wq = (const float*)d_in[1];
    const float* wk = (const float*)d_in[2];
    const float* wv = (const float*)d_in[3];
    qkv_gemm<<<dim3((M_DIM / BM) * ((N_Q + 2 * N_KV) / BN)), dim3(256), 0, stream>>>(
        x, wq, wk, wv, (float*)d_out);
}